// Round 7
// baseline (500.927 us; speedup 1.0000x reference)
//
#include <hip/hip_runtime.h>
#include <math.h>
#include <stdint.h>

#define B_ 4
#define L_ 2048
#define D_ 1024
#define H_ 16

typedef __attribute__((ext_vector_type(4))) float f32x4;
typedef __attribute__((ext_vector_type(2))) float f32x2;
typedef __attribute__((ext_vector_type(8))) short s16x8;
typedef __attribute__((ext_vector_type(4))) short s16x4;
typedef __attribute__((ext_vector_type(4))) unsigned short u16x4;
typedef __attribute__((ext_vector_type(4))) unsigned int u32x4;
typedef __attribute__((ext_vector_type(2))) __bf16 bf16x2;

__device__ __forceinline__ unsigned short f2bf(float f) {
  unsigned int u = __float_as_uint(f);
  u += 0x7fffu + ((u >> 16) & 1u);  // RNE
  return (unsigned short)(u >> 16);
}
__device__ __forceinline__ float b2f(unsigned short s) {
  return __uint_as_float(((unsigned int)s) << 16);
}
// packed f32x2 -> bf16x2 (RTNE); lowers to v_cvt_pk_bf16_f32 on gfx950
__device__ __forceinline__ unsigned int pk2(float a, float b) {
  f32x2 v;
  v[0] = a;
  v[1] = b;
  bf16x2 r = __builtin_convertvector(v, bf16x2);
  return __builtin_bit_cast(unsigned int, r);
}
// silu via fast rcp (1-ulp)
__device__ __forceinline__ float silu_fast(float v) {
  return v * __builtin_amdgcn_rcpf(1.0f + __expf(-v));
}
// async global->LDS DMA, 16B per lane; lds dest = wave-uniform base + lane*16
__device__ __forceinline__ void gl_lds16(const void* g, void* l) {
  __builtin_amdgcn_global_load_lds(
      (__attribute__((address_space(1))) void*)(uintptr_t)g,
      (__attribute__((address_space(3))) void*)(uint32_t)(uintptr_t)l, 16, 0, 0);
}

// ---------------------------------------------------------------------------
// fp32 -> bf16 elementwise (x)
// ---------------------------------------------------------------------------
__global__ __launch_bounds__(256) void conv_x(const float* __restrict__ x,
                                              unsigned short* __restrict__ xb, int n4) {
  int i = blockIdx.x * 256 + threadIdx.x;
  if (i < n4) {
    f32x4 v = *(const f32x4*)(x + (size_t)i * 4);
    u16x4 o;
#pragma unroll
    for (int j = 0; j < 4; ++j) o[j] = f2bf(v[j]);
    *(u16x4*)(xb + (size_t)i * 4) = o;
  }
}

// ---------------------------------------------------------------------------
// W[K][N] fp32 -> Wt[N][K] bf16 (LDS tile transpose)
// ---------------------------------------------------------------------------
__global__ __launch_bounds__(256) void trans_w(const float* __restrict__ W,
                                               unsigned short* __restrict__ Wt,
                                               int K, int N) {
  __shared__ float T[64][65];
  const int k0 = blockIdx.y * 64, n0 = blockIdx.x * 64;
  const int tid = threadIdx.x;
#pragma unroll
  for (int i = 0; i < 16; ++i) {
    int e = tid + i * 256;
    int r = e >> 6, c = e & 63;
    T[r][c] = W[(size_t)(k0 + r) * N + n0 + c];
  }
  __syncthreads();
#pragma unroll
  for (int i = 0; i < 16; ++i) {
    int e = tid + i * 256;
    int r = e >> 6, c = e & 63;
    Wt[(size_t)(n0 + r) * K + k0 + c] = f2bf(T[c][r]);
  }
}

// ---------------------------------------------------------------------------
// RoPE cos/sin table [L][32]
// ---------------------------------------------------------------------------
__global__ __launch_bounds__(256) void rope_tab(f32x2* __restrict__ tab) {
  int i = blockIdx.x * 256 + threadIdx.x;  // L_*32
  int l = i >> 5, j = i & 31;
  float inv = expf(-(float)j * (9.210340371976184f / 32.0f));  // 10000^(-j/32)
  float ang = (float)l * inv;
  f32x2 cs;
  cs[0] = cosf(ang);
  cs[1] = sinf(ang);
  tab[i] = cs;
}

// ---------------------------------------------------------------------------
// bf16 MFMA GEMM (unchanged): C = [silu](A @ Bt^T).
// ---------------------------------------------------------------------------
template <int MODE>
__global__ __launch_bounds__(256) void gemm_bf16(const unsigned short* __restrict__ A,
                                                 const unsigned short* __restrict__ Bt,
                                                 void* __restrict__ Cp,
                                                 int M, int N, int K) {
  alignas(16) __shared__ unsigned short As[128][32];
  alignas(16) __shared__ unsigned short Bs[128][32];
  const int tid = threadIdx.x;
  const int lane = tid & 63, w = tid >> 6;
  const int quad = lane >> 4, l15 = lane & 15;
  const int wr = w >> 1, wc = w & 1;
  const int m0 = blockIdx.y * 128, n0 = blockIdx.x * 128;
  const int srow = lane >> 2;
  const int schunk = (lane & 3) ^ ((lane >> 3) & 3);
  const int fcol = (quad ^ ((l15 >> 1) & 3)) * 8;
  f32x4 acc[4][4] = {};
  for (int k0 = 0; k0 < K; k0 += 32) {
    __syncthreads();
#pragma unroll
    for (int i = 0; i < 2; ++i) {
      int r0 = (w * 2 + i) * 16;
      gl_lds16(A + (size_t)(m0 + r0 + srow) * K + k0 + schunk * 8, &As[r0][0]);
      gl_lds16(Bt + (size_t)(n0 + r0 + srow) * K + k0 + schunk * 8, &Bs[r0][0]);
    }
    __syncthreads();
    s16x8 af[4], bf[4];
#pragma unroll
    for (int mi = 0; mi < 4; ++mi) af[mi] = *(const s16x8*)&As[wr * 64 + mi * 16 + l15][fcol];
#pragma unroll
    for (int nj = 0; nj < 4; ++nj) bf[nj] = *(const s16x8*)&Bs[wc * 64 + nj * 16 + l15][fcol];
#pragma unroll
    for (int mi = 0; mi < 4; ++mi)
#pragma unroll
      for (int nj = 0; nj < 4; ++nj)
        acc[mi][nj] = __builtin_amdgcn_mfma_f32_16x16x32_bf16(af[mi], bf[nj], acc[mi][nj], 0, 0, 0);
  }
#pragma unroll
  for (int mi = 0; mi < 4; ++mi)
#pragma unroll
    for (int nj = 0; nj < 4; ++nj)
#pragma unroll
      for (int reg = 0; reg < 4; ++reg) {
        int rg = m0 + wr * 64 + mi * 16 + quad * 4 + reg;
        int cg = n0 + wc * 64 + nj * 16 + l15;
        float v = acc[mi][nj][reg];
        if (MODE == 1) {
          ((unsigned short*)Cp)[(size_t)rg * N + cg] = f2bf(silu_fast(v));
        } else {
          ((float*)Cp)[(size_t)rg * N + cg] = v;
        }
      }
}

// ---------------------------------------------------------------------------
// In-place RoPE on q,k quarters of qkuv_bf + build v_t[bh][64 d][Lperm] bf16.
// Key axis of vt is PERMUTED within each 32-group so that P fragments (C-layout
// of S^T, pairs of 16-key tiles concatenated) form a valid mfma_16x16x32
// A-operand: position p = 8q+4h+j  <-  local key 16h+4q+j.
// ---------------------------------------------------------------------------
__global__ __launch_bounds__(256) void rope_conv(unsigned short* __restrict__ qk,
                                                 unsigned short* __restrict__ vt,
                                                 const f32x2* __restrict__ tab) {
  alignas(16) __shared__ unsigned short Vsh[64][72];
  const int tid = threadIdx.x;
  const int bh = blockIdx.y, b = bh >> 4, h = bh & 15;
  const int l0 = blockIdx.x * 64;
#pragma unroll
  for (int i = 0; i < 2; ++i) {
    int p = tid + i * 256;
    int row = p >> 3, c4 = p & 7;
    int l = l0 + row;
    size_t base = (size_t)(b * L_ + l) * 4096 + h * 64 + c4 * 4;
#pragma unroll
    for (int t = 0; t < 2; ++t) {  // 0: q, 1: k
      size_t o = base + (size_t)t * 1024;
      u16x4 lo = *(u16x4*)(qk + o);
      u16x4 hi = *(u16x4*)(qk + o + 32);
      u16x4 nlo, nhi;
#pragma unroll
      for (int jj = 0; jj < 4; ++jj) {
        f32x2 cs = tab[l * 32 + c4 * 4 + jj];
        float fl = b2f(lo[jj]), fh = b2f(hi[jj]);
        nlo[jj] = f2bf(fl * cs[0] - fh * cs[1]);
        nhi[jj] = f2bf(fh * cs[0] + fl * cs[1]);
      }
      *(u16x4*)(qk + o) = nlo;
      *(u16x4*)(qk + o + 32) = nhi;
    }
  }
#pragma unroll
  for (int i = 0; i < 2; ++i) {
    int ch = tid + i * 256;
    int row = ch >> 3, c8 = ch & 7;
    *(s16x8*)&Vsh[row][c8 * 8] =
        *(const s16x8*)(qk + (size_t)(b * L_ + l0 + row) * 4096 + 2048 + h * 64 + c8 * 8);
  }
  __syncthreads();
#pragma unroll
  for (int i = 0; i < 2; ++i) {
    int ch = tid + i * 256;
    int drow = ch >> 3, c8 = ch & 7;
    s16x8 o;
#pragma unroll
    for (int jj = 0; jj < 8; ++jj) {
      int pos = c8 * 8 + jj;  // 0..63 within tile
      int g = pos >> 5, p = pos & 31;
      int lk = g * 32 + ((p >> 2) & 1) * 16 + ((p >> 3) & 3) * 4 + (p & 3);
      o[jj] = (short)Vsh[lk][drow];
    }
    *(s16x8*)(vt + (size_t)(bh * 64 + drow) * 2048 + l0 + c8 * 8) = o;
  }
}

// ---------------------------------------------------------------------------
// Fused MFMA attention v5: v4 + double-buffered K/V with async prefetch.
// One barrier per key-tile; tile i+1's global_load_lds DMA is issued right
// after the barrier (into the alternate LDS buffer), so the vmcnt(0) drain at
// the NEXT barrier happens a full compute phase after issue (~free), instead
// of immediately after issue (~900-cycle stall) as in the 2-barrier form.
// ---------------------------------------------------------------------------
__global__ __launch_bounds__(256) void attn_mfma(
    const unsigned short* __restrict__ qk, const unsigned short* __restrict__ vt,
    const float* __restrict__ amask, const float* __restrict__ cmask,
    const float* __restrict__ cbias, const float* __restrict__ gamma,
    const float* __restrict__ beta, unsigned short* __restrict__ attng) {
  alignas(16) __shared__ unsigned short Ks[2][64][64];   // [buf][key][d], chunks XORed
  alignas(16) __shared__ unsigned short Vts[2][64][64];  // [buf][d][key], chunks XORed
  const int tid = threadIdx.x;
  const int lane = tid & 63, w = tid >> 6;
  const int quad = lane >> 4, l15 = lane & 15;
  const int bh = blockIdx.y, b = bh >> 4, h = bh & 15;
  const int l0 = blockIdx.x * 128;
  const float cb = cbias[h];
  const int srow = lane >> 3;            // 0..7 within a 1KB DMA
  const int schunk = (lane & 7) ^ srow;  // source chunk for XOR-8 store

  // Hoist Q fragments for this wave's 32 q-rows (b-operand of S^T mfma)
  s16x8 qf[2][2];
  const float* abase[2];
#pragma unroll
  for (int qs = 0; qs < 2; ++qs) {
    int qg = l0 + w * 32 + qs * 16 + l15;
#pragma unroll
    for (int s = 0; s < 2; ++s)
      qf[qs][s] = *(const s16x8*)(qk + (size_t)(b * L_ + qg) * 4096 + h * 64 + s * 32 + quad * 8);
    abase[qs] = amask + ((size_t)b * L_ + qg) * L_;
  }
  const float* cbase = cmask + (size_t)b * L_;

  // Stage tile 0 into buffer 0 (wave w stages rows w*16 .. w*16+15)
#pragma unroll
  for (int i = 0; i < 2; ++i) {
    int r0 = w * 16 + i * 8;
    gl_lds16(qk + (size_t)(b * L_ + r0 + srow) * 4096 + 1024 + h * 64 + schunk * 8,
             &Ks[0][r0][0]);
    gl_lds16(vt + (size_t)(bh * 64 + r0 + srow) * 2048 + 0 + schunk * 8, &Vts[0][r0][0]);
  }

  f32x4 oacc[2][4] = {};  // [qs][dt] C-layout: row=q=quad*4+reg, col=d=dt*16+l15

  for (int it = 0; it < L_ / 64; ++it) {
    const int m0 = it * 64;
    const int cur = it & 1;
    __syncthreads();  // tile `it` DMA complete & visible; prev-buf reads done

    if (it + 1 < L_ / 64) {  // prefetch tile it+1 into the alternate buffer
      const int nxt = cur ^ 1;
      const int m1 = m0 + 64;
#pragma unroll
      for (int i = 0; i < 2; ++i) {
        int r0 = w * 16 + i * 8;
        gl_lds16(qk + (size_t)(b * L_ + m1 + r0 + srow) * 4096 + 1024 + h * 64 + schunk * 8,
                 &Ks[nxt][r0][0]);
        gl_lds16(vt + (size_t)(bh * 64 + r0 + srow) * 2048 + m1 + schunk * 8,
                 &Vts[nxt][r0][0]);
      }
    }

    // Masks for tile `it` (first use is after the S-MFMA block -> latency hidden)
    f32x4 cmcb[4], am4[2][4];
#pragma unroll
    for (int kt = 0; kt < 4; ++kt)
      cmcb[kt] = *(const f32x4*)(cbase + m0 + kt * 16 + quad * 4) * cb;
#pragma unroll
    for (int qs = 0; qs < 2; ++qs)
#pragma unroll
      for (int kt = 0; kt < 4; ++kt)
        am4[qs][kt] = *(const f32x4*)(abase[qs] + m0 + kt * 16 + quad * 4);

    // S^T = K @ Q^T over d=64 (two K=32 steps)
    f32x4 sacc[2][4] = {};  // [qs][kt]; C: key=quad*4+reg, q=l15
#pragma unroll
    for (int s = 0; s < 2; ++s) {
      s16x8 kf[4];
#pragma unroll
      for (int kt = 0; kt < 4; ++kt)
        kf[kt] = *(const s16x8*)&Ks[cur][kt * 16 + l15][((s * 4 + quad) ^ (l15 & 7)) * 8];
#pragma unroll
      for (int qs = 0; qs < 2; ++qs)
#pragma unroll
        for (int kt = 0; kt < 4; ++kt)
          sacc[qs][kt] = __builtin_amdgcn_mfma_f32_16x16x32_bf16(kf[kt], qf[qs][s],
                                                                 sacc[qs][kt], 0, 0, 0);
    }

    // Epilogue -> P fragments packed as K=32 A-operands (kt pairs)
    s16x8 pf[2][2];
#pragma unroll
    for (int qs = 0; qs < 2; ++qs)
#pragma unroll
      for (int t = 0; t < 2; ++t) {
        u32x4 pw;
#pragma unroll
        for (int half = 0; half < 2; ++half) {
          int kt = 2 * t + half;
          float x[4];
#pragma unroll
          for (int r = 0; r < 4; ++r) {
            float v = fmaf(sacc[qs][kt][r], 0.125f, cmcb[kt][r]);
            v = silu_fast(v);
            x[r] = v * am4[qs][kt][r];
          }
          pw[half * 2 + 0] = pk2(x[0], x[1]);
          pw[half * 2 + 1] = pk2(x[2], x[3]);
        }
        pf[qs][t] = __builtin_bit_cast(s16x8, pw);
      }

    // O += P @ V, K=32 per group (vt key-permuted to match P's lane layout)
#pragma unroll
    for (int dt = 0; dt < 4; ++dt)
#pragma unroll
      for (int t = 0; t < 2; ++t) {
        s16x8 vf = *(const s16x8*)&Vts[cur][dt * 16 + l15][((t * 4 + quad) ^ (l15 & 7)) * 8];
#pragma unroll
        for (int qs = 0; qs < 2; ++qs)
          oacc[qs][dt] = __builtin_amdgcn_mfma_f32_16x16x32_bf16(pf[qs][t], vf,
                                                                 oacc[qs][dt], 0, 0, 0);
      }
  }

  // LayerNorm over d=64 + u-gate + store
#pragma unroll
  for (int qs = 0; qs < 2; ++qs) {
    float sm[4], sq[4];
#pragma unroll
    for (int reg = 0; reg < 4; ++reg) {
      float s1 = 0.f, s2 = 0.f;
#pragma unroll
      for (int dt = 0; dt < 4; ++dt) {
        float v = oacc[qs][dt][reg];
        s1 += v;
        s2 += v * v;
      }
      sm[reg] = s1;
      sq[reg] = s2;
    }
#pragma unroll
    for (int m = 1; m < 16; m <<= 1) {
#pragma unroll
      for (int reg = 0; reg < 4; ++reg) {
        sm[reg] += __shfl_xor(sm[reg], m);
        sq[reg] += __shfl_xor(sq[reg], m);
      }
    }
    float mu[4], rs[4];
#pragma unroll
    for (int reg = 0; reg < 4; ++reg) {
      mu[reg] = sm[reg] * (1.0f / 64.0f);
      float var = sq[reg] * (1.0f / 64.0f) - mu[reg] * mu[reg];
      rs[reg] = rsqrtf(var + 1e-5f);
    }
#pragma unroll
    for (int dt = 0; dt < 4; ++dt) {
      float g = gamma[dt * 16 + l15], be = beta[dt * 16 + l15];
#pragma unroll
      for (int reg = 0; reg < 4; ++reg) {
        int rowg = l0 + w * 32 + qs * 16 + quad * 4 + reg;
        int colg = dt * 16 + l15;
        float v = (oacc[qs][dt][reg] - mu[reg]) * rs[reg] * g + be;
        float u = b2f(qk[(size_t)(b * L_ + rowg) * 4096 + 3072 + h * 64 + colg]);
        attng[(size_t)(b * L_ + rowg) * 1024 + h * 64 + colg] = f2bf(v * u);
      }
    }
  }
}

extern "C" void kernel_launch(void* const* d_in, const int* in_sizes, int n_in,
                              void* d_out, int out_size, void* d_ws, size_t ws_size,
                              hipStream_t stream) {
  const float* x = (const float*)d_in[0];
  const float* amask = (const float*)d_in[1];
  const float* cmask = (const float*)d_in[2];
  const float* Wqkuv = (const float*)d_in[3];
  const float* Wout = (const float*)d_in[4];
  const float* gamma = (const float*)d_in[5];
  const float* beta = (const float*)d_in[6];
  const float* cbias = (const float*)d_in[7];
  float* out = (float*)d_out;

  char* ws = (char*)d_ws;
  unsigned short* qkuv_bf = (unsigned short*)ws;                    // 64 MB
  unsigned short* vt = (unsigned short*)(ws + ((size_t)64 << 20));  // 16 MB
  unsigned short* xbf = (unsigned short*)(ws + ((size_t)80 << 20));  // 16 MB
  unsigned short* Wt = (unsigned short*)(ws + ((size_t)96 << 20));   // 8 MB
  unsigned short* Wot = (unsigned short*)(ws + ((size_t)104 << 20)); // 2 MB
  unsigned short* attng = (unsigned short*)(ws + ((size_t)106 << 20)); // 16 MB
  f32x2* tab = (f32x2*)(ws + ((size_t)122 << 20));                   // 0.5 MB

  conv_x<<<8192, 256, 0, stream>>>(x, xbf, (B_ * L_ * D_) / 4);
  trans_w<<<dim3(4096 / 64, 1024 / 64), 256, 0, stream>>>(Wqkuv, Wt, 1024, 4096);
  trans_w<<<dim3(1024 / 64, 1024 / 64), 256, 0, stream>>>(Wout, Wot, 1024, 1024);
  rope_tab<<<(L_ * 32) / 256, 256, 0, stream>>>(tab);

  gemm_bf16<1><<<dim3(4096 / 128, 8192 / 128), 256, 0, stream>>>(xbf, Wt, qkuv_bf,
                                                                 B_ * L_, 4 * D_, D_);
  rope_conv<<<dim3(L_ / 64, B_ * H_), 256, 0, stream>>>(qkuv_bf, vt, tab);
  attn_mfma<<<dim3(L_ / 128, B_ * H_), 256, 0, stream>>>(qkuv_bf, vt, amask, cmask, cbias,
                                                         gamma, beta, attng);
  gemm_bf16<0><<<dim3(1024 / 128, 8192 / 128), 256, 0, stream>>>(attng, Wot, out,
                                                                 B_ * L_, D_, D_);
}